// Round 12
// baseline (2243.802 us; speedup 1.0000x reference)
//
#include <hip/hip_runtime.h>
#include <hip/hip_bf16.h>

typedef __attribute__((ext_vector_type(4))) float f32x4;
typedef __attribute__((ext_vector_type(8))) short bf16x8;
typedef __attribute__((ext_vector_type(2))) unsigned int u32x2;
typedef __attribute__((ext_vector_type(4))) unsigned int u32x4;

// Instrumentation reps (pure kernels; output-identical each rep).
#define REPS_P 8
#define REPS_A 6
#define REPS_G 6

static __device__ __forceinline__ unsigned short f2bf(float f) {
    unsigned u = __builtin_bit_cast(unsigned, f);
    u += 0x7fffu + ((u >> 16) & 1u);   // RNE
    return (unsigned short)(u >> 16);
}
static __device__ __forceinline__ unsigned pack2(float a, float b) {
    __hip_bfloat162 h = __float22bfloat162_rn(make_float2(a, b));  // v_cvt_pk_bf16_f32
    unsigned u;
    __builtin_memcpy(&u, &h, 4);
    return u;
}
static __device__ __forceinline__ float bf2f(unsigned short s) {
    unsigned u = (unsigned)s << 16;
    float f;
    __builtin_memcpy(&f, &u, 4);
    return f;
}

// Barrier WITHOUT vmcnt drain.
static __device__ __forceinline__ void bar_nodrain() {
    __builtin_amdgcn_sched_barrier(0);
    asm volatile("s_waitcnt lgkmcnt(0)" ::: "memory");
    __builtin_amdgcn_s_barrier();
    __builtin_amdgcn_sched_barrier(0);
}

// ---------------------------------------------------------------------------
// hidden fp32 -> bf16
// ---------------------------------------------------------------------------
__global__ __launch_bounds__(256)
void cvt_bf16(const float* __restrict__ in, unsigned* __restrict__ out, int n8)
{
    const int i = blockIdx.x * 256 + threadIdx.x;
    if (i >= n8) return;
    f32x4 a = ((const f32x4*)in)[2 * i];
    f32x4 b = ((const f32x4*)in)[2 * i + 1];
    u32x4 p = { pack2(a[0], a[1]), pack2(a[2], a[3]), pack2(b[0], b[1]), pack2(b[2], b[3]) };
    ((u32x4*)out)[i] = p;
}

// ---------------------------------------------------------------------------
// BN=64 GEMM body, SHARED-K band sweep: bx = bidx % ntiles (tile-fast), so
// all co-resident blocks of one K-split group read the SAME 64-row B band
// each step -> union access stream is globally sequential; L3 absorbs drift.
// by = bidx / ntiles (K-split group; ntiles == grid -> no split).
// A 1-deep, B 2-deep register prefetch; no-drain barriers.
// SCALE: fold softmax 1/sqrt(128) into epilogue (q path).
// ---------------------------------------------------------------------------
template<int CBF16, int COLMAP, int SCALE>
__device__ __forceinline__
void gemm_body(const unsigned short* __restrict__ Ah, int lda,
               const float* __restrict__ Bm, int ldb,
               void* __restrict__ Cp, int ldc,
               int kchunk, int ntiles, int bidx,
               unsigned short* As, unsigned short* Bs)
{
    const int tid = threadIdx.x;
    const int w = tid >> 6, l = tid & 63, lg = l >> 4, l15 = l & 15;
    const int bx = bidx % ntiles;
    const int by = bidx / ntiles;
    const int n0 = bx * 64;
    const int pcol = COLMAP ? ((n0 >> 7) * 192 + (n0 & 127)) : n0;
    const size_t k0base = (size_t)by * (size_t)kchunk;

    const int ar = tid >> 1;          // A row
    const int ac = (tid & 1) * 32;    // A col base (ushorts)
    const int bnb = (tid & 15) * 4;   // B col
    const int bkk = tid >> 4;         // B k-pair

    u32x4 aReg[4];
    f32x4 b0Reg[2][2], b1Reg[2][2];

    auto loadA = [&](size_t k0) {
#pragma unroll
        for (int k = 0; k < 4; k++)
            aReg[k] = *(const u32x4*)(Ah + (size_t)ar * lda + k0 + ac + 8 * k);
    };
    auto storeA = [&]() {
#pragma unroll
        for (int k = 0; k < 4; k++)
            *(u32x4*)&As[ar * 72 + ac + 8 * k] = aReg[k];
    };
    auto loadB = [&](f32x4 (&bR)[2][2], size_t k0) {
#pragma unroll
        for (int i = 0; i < 2; i++) {
            const float* bp = Bm + (k0 + (size_t)(2 * (bkk + 16 * i))) * (size_t)ldb + pcol + bnb;
            bR[i][0] = *(const f32x4*)bp;
            bR[i][1] = *(const f32x4*)(bp + ldb);
        }
    };
    auto storeB = [&](f32x4 (&bR)[2][2]) {
        unsigned* bd = (unsigned*)Bs;
#pragma unroll
        for (int i = 0; i < 2; i++)
#pragma unroll
            for (int j = 0; j < 4; j++)
                bd[(bnb + j) * 33 + bkk + 16 * i] = pack2(bR[i][0][j], bR[i][1][j]);
    };

    f32x4 acc[2][4];
    const f32x4 fzero = {0.f, 0.f, 0.f, 0.f};
#pragma unroll
    for (int a = 0; a < 2; a++)
#pragma unroll
        for (int b2 = 0; b2 < 4; b2++) acc[a][b2] = fzero;

    auto mfmaStep = [&]() {
#pragma unroll
        for (int ks = 0; ks < 2; ks++) {
            bf16x8 bfr[4];
#pragma unroll
            for (int nf = 0; nf < 4; nf++)
                bfr[nf] = *(const bf16x8*)&Bs[(16 * nf + l15) * 66 + 32 * ks + 8 * lg];
#pragma unroll
            for (int mf = 0; mf < 2; mf++) {
                bf16x8 af = *(const bf16x8*)&As[(32 * w + 16 * mf + l15) * 72 + 32 * ks + 8 * lg];
#pragma unroll
                for (int nf = 0; nf < 4; nf++)
                    acc[mf][nf] = __builtin_amdgcn_mfma_f32_16x16x32_bf16(af, bfr[nf], acc[mf][nf], 0, 0, 0);
            }
        }
    };

    const int nst = kchunk >> 6;
    auto kof = [&](int t) { return k0base + (size_t)(t << 6); };

    loadA(kof(0));
    loadB(b0Reg, kof(0));
    if (nst > 1) loadB(b1Reg, kof(1));

    for (int t = 0; t < nst; t += 2) {
        storeA(); storeB(b0Reg);
        bar_nodrain();
        if (t + 1 < nst) loadA(kof(t + 1));
        if (t + 2 < nst) loadB(b0Reg, kof(t + 2));
        __builtin_amdgcn_sched_barrier(0);
        mfmaStep();
        bar_nodrain();
        if (t + 1 < nst) {
            storeA(); storeB(b1Reg);
            bar_nodrain();
            if (t + 2 < nst) loadA(kof(t + 2));
            if (t + 3 < nst) loadB(b1Reg, kof(t + 3));
            __builtin_amdgcn_sched_barrier(0);
            mfmaStep();
            bar_nodrain();
        }
    }
    const float cscale = SCALE ? 0.088388347648318447f : 1.0f;
#pragma unroll
    for (int mf = 0; mf < 2; mf++) {
#pragma unroll
        for (int nf = 0; nf < 4; nf++) {
            const int m0 = 32 * w + 16 * mf + 4 * lg;
            const int cn = n0 + 16 * nf + l15;
            if (CBF16) {
                unsigned short* Ch = (unsigned short*)Cp + (size_t)by * ((size_t)128 * (size_t)ldc);
#pragma unroll
                for (int r = 0; r < 4; r++)
                    Ch[(size_t)(m0 + r) * ldc + cn] = f2bf(acc[mf][nf][r] * cscale);
            } else {
                float* Cf = (float*)Cp + (size_t)by * ((size_t)128 * (size_t)ldc);
#pragma unroll
                for (int r = 0; r < 4; r++)
                    Cf[(size_t)(m0 + r) * ldc + cn] = acc[mf][nf][r];
            }
        }
    }
}

// ---------------------------------------------------------------------------
// Fused projection: blocks [0,256) -> q = hidden@Wq nope cols, NO K-split,
// scaled bf16 直接 to qb (band-shared K sweep). Blocks [256,320) -> kv
// partials (fp32, 4 tiles x 16 splits).
// ---------------------------------------------------------------------------
#define QBLOCKS 256

__global__ __launch_bounds__(256, 2)
void proj_fused(const unsigned short* __restrict__ hb,
                const float* __restrict__ Wq, const float* __restrict__ Wkv,
                unsigned short* __restrict__ qb, float* __restrict__ kvp)
{
    __shared__ __align__(16) unsigned short As[128 * 72];
    __shared__ __align__(16) unsigned short Bs[64 * 66];
#pragma unroll 1
    for (int rep = 0; rep < REPS_P; ++rep) {
        if (blockIdx.x < QBLOCKS)
            gemm_body<1, 1, 1>(hb, 5120, Wq, 24576, qb, 16384, 5120, 256, blockIdx.x, As, Bs);
        else
            gemm_body<0, 0, 0>(hb, 5120, Wkv, 576, kvp, 256, 320, 4, blockIdx.x - QBLOCKS, As, Bs);
        bar_nodrain();
    }
}

// ---------------------------------------------------------------------------
// out partials = attn(bf16) @ Wo, bf16 partials (80 tiles x 8 splits,
// tile-fast -> each by-group band-sweeps together)
// ---------------------------------------------------------------------------
__global__ __launch_bounds__(256, 2)
void gemm_out(const unsigned short* __restrict__ Ah, const float* __restrict__ Wo,
              unsigned short* __restrict__ outp)
{
    __shared__ __align__(16) unsigned short As[128 * 72];
    __shared__ __align__(16) unsigned short Bs[64 * 66];
#pragma unroll 1
    for (int rep = 0; rep < REPS_G; ++rep) {
        gemm_body<1, 0, 0>(Ah, 16384, Wo, 5120, outp, 5120, 2048, 80, blockIdx.x, As, Bs);
        bar_nodrain();
    }
}

// ---------------------------------------------------------------------------
// Flash-decode attention (unchanged). KVBLK=64, grid (B, NSPLIT=8), block 512.
// ---------------------------------------------------------------------------
#define NSPLIT 8
#define CHUNK_T 8
#define KVSPLIT 16

__global__ __launch_bounds__(512, 4)
void attn_fwd(const float* __restrict__ kc, const float* __restrict__ vc,
              const unsigned short* __restrict__ qb, const float* __restrict__ kvp,
              const int* __restrict__ seq_lens, const int* __restrict__ slot_map,
              unsigned short* __restrict__ Opart, float* __restrict__ m_ws, float* __restrict__ l_ws)
{
    __shared__ __align__(16) unsigned short Ks [64 * 136];
    __shared__ __align__(16) unsigned short Vts[128 * 72];
    __shared__ __align__(16) unsigned short Ps [128 * 72];
    __shared__ float knew_s[128];
    __shared__ float vnew_s[128];

    const int b = blockIdx.x, split = blockIdx.y;
    const int seq = seq_lens[b], slot = slot_map[b];
    const int nt = (seq + 63) >> 6;
    const int t0 = split * CHUNK_T;
    const int t1 = min(t0 + CHUNK_T, nt);
    const int slotTile = slot >> 6;

    const int tid = threadIdx.x, w = tid >> 6, l = tid & 63, lg = l >> 4, l15 = l & 15;
    const int h = 16 * w + l15;

#pragma unroll 1
    for (int rep = 0; rep < REPS_A; ++rep) {
    float m_run = -__builtin_inff(), l_run = 0.0f;

    if (t0 < t1) {
        if (slotTile >= t0 && slotTile < t1 && tid < 256) {
            float s = 0.f;
#pragma unroll
            for (int j = 0; j < KVSPLIT; j++) s += kvp[j * 32768 + b * 256 + tid];
            if (tid < 128) knew_s[tid] = s;
            else           vnew_s[tid - 128] = s;
        }

        bf16x8 qf[4];
        {
            const unsigned short* qrow = qb + (size_t)b * 16384 + (size_t)h * 128;
#pragma unroll
            for (int ks = 0; ks < 4; ks++)
                qf[ks] = *(const bf16x8*)(qrow + 32 * ks + 8 * lg);
        }

        f32x4 kReg[4];
        f32x4 vReg[2][2];
        const int kr  = tid >> 3;
        const int kcb = (tid & 7) * 16;
        const int vsp = tid & 31;
        const int vdq = tid >> 5;

        auto loadKV = [&](int t) {
            const int s0 = t << 6;
            const float* ksrc = kc + ((size_t)b * 4096 + s0 + kr) * 128 + kcb;
#pragma unroll
            for (int c = 0; c < 4; c++) kReg[c] = *(const f32x4*)(ksrc + 4 * c);
#pragma unroll
            for (int i = 0; i < 2; i++) {
                const int d4 = 4 * vdq + 64 * i;
                const float* r1 = vc + ((size_t)b * 4096 + s0 + 2 * vsp) * 128 + d4;
                vReg[i][0] = *(const f32x4*)r1;
                vReg[i][1] = *(const f32x4*)(r1 + 128);
            }
        };
        auto storeKV = [&]() {
            u32x4 w0 = { pack2(kReg[0][0], kReg[0][1]), pack2(kReg[0][2], kReg[0][3]),
                         pack2(kReg[1][0], kReg[1][1]), pack2(kReg[1][2], kReg[1][3]) };
            u32x4 w1 = { pack2(kReg[2][0], kReg[2][1]), pack2(kReg[2][2], kReg[2][3]),
                         pack2(kReg[3][0], kReg[3][1]), pack2(kReg[3][2], kReg[3][3]) };
            *(u32x4*)&Ks[kr * 136 + kcb] = w0;
            *(u32x4*)&Ks[kr * 136 + kcb + 8] = w1;
            unsigned* vt = (unsigned*)Vts;
#pragma unroll
            for (int i = 0; i < 2; i++)
#pragma unroll
                for (int j = 0; j < 4; j++)
                    vt[(4 * vdq + 64 * i + j) * 36 + vsp] = pack2(vReg[i][0][j], vReg[i][1][j]);
        };

        f32x4 accO[8];
        const f32x4 fzero = {0.f, 0.f, 0.f, 0.f};
#pragma unroll
        for (int i = 0; i < 8; i++) accO[i] = fzero;

        loadKV(t0);
        for (int t = t0; t < t1; ++t) {
            const int s0 = t << 6;
            storeKV();
            bar_nodrain();
            if (t == slotTile) {
                if (tid < 128) {
                    const int sloc = slot & 63;
                    Ks [sloc * 136 + tid] = f2bf(knew_s[tid]);
                    Vts[tid * 72 + sloc]  = f2bf(vnew_s[tid]);
                }
                bar_nodrain();
            }
            if (t + 1 < t1) loadKV(t + 1);
            __builtin_amdgcn_sched_barrier(0);

            f32x4 accS[4];
#pragma unroll
            for (int sf = 0; sf < 4; sf++) accS[sf] = fzero;
#pragma unroll
            for (int ks = 0; ks < 4; ks++) {
#pragma unroll
                for (int sf = 0; sf < 4; sf++) {
                    bf16x8 kf = *(const bf16x8*)&Ks[(16 * sf + l15) * 136 + 32 * ks + 8 * lg];
                    accS[sf] = __builtin_amdgcn_mfma_f32_16x16x32_bf16(kf, qf[ks], accS[sf], 0, 0, 0);
                }
            }
            float tmax = -__builtin_inff();
#pragma unroll
            for (int sf = 0; sf < 4; sf++) {
#pragma unroll
                for (int r = 0; r < 4; r++) {
                    const int s = s0 + 16 * sf + 4 * lg + r;
                    float sc = (s < seq) ? accS[sf][r] : -__builtin_inff();
                    accS[sf][r] = sc;
                    tmax = fmaxf(tmax, sc);
                }
            }
            tmax = fmaxf(tmax, __shfl_xor(tmax, 16));
            tmax = fmaxf(tmax, __shfl_xor(tmax, 32));
            const float mnew = fmaxf(m_run, tmax);
            const float so = __expf(m_run - mnew);
            float lsum = 0.f;
#pragma unroll
            for (int sf = 0; sf < 4; sf++) {
#pragma unroll
                for (int r = 0; r < 4; r++) {
                    const float p = __expf(accS[sf][r] - mnew);
                    accS[sf][r] = p;
                    lsum += p;
                }
            }
            lsum += __shfl_xor(lsum, 16);
            lsum += __shfl_xor(lsum, 32);
            l_run = l_run * so + lsum;
            m_run = mnew;
#pragma unroll
            for (int i = 0; i < 8; i++) accO[i] *= so;

            {
                unsigned* pd = (unsigned*)Ps;
#pragma unroll
                for (int sf = 0; sf < 4; sf++) {
                    pd[h * 36 + 8 * sf + 2 * lg + 0] = pack2(accS[sf][0], accS[sf][1]);
                    pd[h * 36 + 8 * sf + 2 * lg + 1] = pack2(accS[sf][2], accS[sf][3]);
                }
            }
            bf16x8 pf[2];
#pragma unroll
            for (int ks = 0; ks < 2; ks++)
                pf[ks] = *(const bf16x8*)&Ps[h * 72 + 32 * ks + 8 * lg];
#pragma unroll
            for (int df = 0; df < 8; df++) {
#pragma unroll
                for (int ks = 0; ks < 2; ks++) {
                    bf16x8 vf = *(const bf16x8*)&Vts[(16 * df + l15) * 72 + 32 * ks + 8 * lg];
                    accO[df] = __builtin_amdgcn_mfma_f32_16x16x32_bf16(vf, pf[ks], accO[df], 0, 0, 0);
                }
            }
            bar_nodrain();
        }
        unsigned short* ob = Opart + ((size_t)(b * NSPLIT + split)) * 16384 + (size_t)h * 128;
#pragma unroll
        for (int df = 0; df < 8; df++) {
            u32x2 p = { pack2(accO[df][0], accO[df][1]), pack2(accO[df][2], accO[df][3]) };
            *(u32x2*)&ob[16 * df + 4 * lg] = p;
        }
    }
    if (lg == 0) {
        m_ws[(b * NSPLIT + split) * 128 + h] = m_run;
        l_ws[(b * NSPLIT + split) * 128 + h] = l_run;
    }
    bar_nodrain();
    }  // rep
}

// ---------------------------------------------------------------------------
// Combine the 8 S-split bf16 partials -> bf16 attn.
// ---------------------------------------------------------------------------
__global__ __launch_bounds__(256)
void combine8(const unsigned short* __restrict__ Opart, const float* __restrict__ m_ws,
              const float* __restrict__ l_ws, unsigned* __restrict__ attn_bf)
{
    const int idx = blockIdx.x * 256 + threadIdx.x;
    const int d4 = (idx & 31) * 4;
    const int hh = (idx >> 5) & 127;
    const int b = idx >> 12;

    float m = -__builtin_inff();
    float mv[NSPLIT], lv[NSPLIT];
#pragma unroll
    for (int j = 0; j < NSPLIT; j++) {
        mv[j] = m_ws[(b * NSPLIT + j) * 128 + hh];
        lv[j] = l_ws[(b * NSPLIT + j) * 128 + hh];
        m = fmaxf(m, mv[j]);
    }
    f32x4 o = {0.f, 0.f, 0.f, 0.f};
    float lsum = 0.f;
#pragma unroll
    for (int j = 0; j < NSPLIT; j++) {
        const float a = (lv[j] > 0.f) ? __expf(mv[j] - m) : 0.f;
        lsum += a * lv[j];
        if (a > 0.f) {
            u32x2 v = *(const u32x2*)&Opart[((size_t)(b * NSPLIT + j)) * 16384 + (size_t)hh * 128 + d4];
            f32x4 oj = { bf2f((unsigned short)(v[0] & 0xffff)), bf2f((unsigned short)(v[0] >> 16)),
                         bf2f((unsigned short)(v[1] & 0xffff)), bf2f((unsigned short)(v[1] >> 16)) };
            o += oj * a;
        }
    }
    o *= (1.0f / lsum);
    u32x2 p = { pack2(o[0], o[1]), pack2(o[2], o[3]) };
    *(u32x2*)&attn_bf[(size_t)b * 8192 + (size_t)hh * 64 + (d4 >> 1)] = p;
}

// ---------------------------------------------------------------------------
// reduce 8 bf16 out partials -> fp32 out
// ---------------------------------------------------------------------------
__global__ __launch_bounds__(256)
void reduce_out_f32(const unsigned short* __restrict__ in, float* __restrict__ out)
{
    const int i = blockIdx.x * 256 + threadIdx.x;   // 0..163839, 4 floats each
    f32x4 s = {0.f, 0.f, 0.f, 0.f};
#pragma unroll
    for (int j = 0; j < 8; j++) {
        u32x2 v = *(const u32x2*)&in[(size_t)j * 655360 + 4 * (size_t)i];
        s[0] += bf2f((unsigned short)(v[0] & 0xffff));
        s[1] += bf2f((unsigned short)(v[0] >> 16));
        s[2] += bf2f((unsigned short)(v[1] & 0xffff));
        s[3] += bf2f((unsigned short)(v[1] >> 16));
    }
    ((f32x4*)out)[i] = s;
}

// ---------------------------------------------------------------------------
extern "C" void kernel_launch(void* const* d_in, const int* in_sizes, int n_in,
                              void* d_out, int out_size, void* d_ws, size_t ws_size,
                              hipStream_t stream)
{
    const float* hidden  = (const float*)d_in[0];
    const float* k_cache = (const float*)d_in[1];
    const float* v_cache = (const float*)d_in[2];
    const float* Wq      = (const float*)d_in[3];
    const float* Wkv     = (const float*)d_in[4];
    const float* Wo      = (const float*)d_in[5];
    const int* slot_map  = (const int*)d_in[7];
    const int* seq_lens  = (const int*)d_in[8];
    float* out = (float*)d_out;

    float* ws = (float*)d_ws;                                    // float units
    unsigned short* hb      = (unsigned short*)(ws);             //    327,680 f
    unsigned short* qb      = (unsigned short*)(ws + 327680);    //  1,048,576 f (scaled bf16 q)
    float*          kvp     = ws + 1376256;                      //    524,288 f (16 splits f32)
    unsigned short* attn_bf = (unsigned short*)(ws + 1900544);   //  1,048,576 f
    unsigned short* Opart   = (unsigned short*)(ws + 2949120);   //  8,388,608 f
    float*          m_ws    = ws + 11337728;                     //    131,072 f
    float*          l_ws    = ws + 11468800;                     //    131,072 f
    unsigned short* outp    = (unsigned short*)(ws + 11599872);  //  2,621,440 f (8 splits bf16)

    // hidden -> bf16
    cvt_bf16<<<dim3(320), 256, 0, stream>>>(hidden, (unsigned*)hb, 81920);
    // q (no K-split, band-shared sweep, direct scaled-bf16) + kv partials
    proj_fused<<<dim3(QBLOCKS + 64), 256, 0, stream>>>(hb, Wq, Wkv, qb, kvp);
    // attention (8 chunked S-splits per batch; kv-reduce fused; bf16 Opart)
    attn_fwd<<<dim3(128, NSPLIT), 512, 0, stream>>>(k_cache, v_cache, qb, kvp,
                                                    seq_lens, slot_map, Opart, m_ws, l_ws);
    combine8<<<dim3(2048), 256, 0, stream>>>(Opart, m_ws, l_ws, (unsigned*)attn_bf);
    // out partials = attn(bf16) @ Wo (80 tiles x 8 splits, tile-fast)
    gemm_out<<<dim3(80 * 8), 256, 0, stream>>>(attn_bf, Wo, outp);
    reduce_out_f32<<<dim3(640), 256, 0, stream>>>(outp, out);
}

// Round 13
// 311.655 us; speedup vs baseline: 7.1996x; 7.1996x over previous
//
#include <hip/hip_runtime.h>
#include <hip/hip_bf16.h>

typedef __attribute__((ext_vector_type(4))) float f32x4;
typedef __attribute__((ext_vector_type(8))) short bf16x8;
typedef __attribute__((ext_vector_type(2))) unsigned int u32x2;
typedef __attribute__((ext_vector_type(4))) unsigned int u32x4;

static __device__ __forceinline__ unsigned short f2bf(float f) {
    unsigned u = __builtin_bit_cast(unsigned, f);
    u += 0x7fffu + ((u >> 16) & 1u);   // RNE
    return (unsigned short)(u >> 16);
}
static __device__ __forceinline__ unsigned pack2(float a, float b) {
    __hip_bfloat162 h = __float22bfloat162_rn(make_float2(a, b));  // v_cvt_pk_bf16_f32
    unsigned u;
    __builtin_memcpy(&u, &h, 4);
    return u;
}
static __device__ __forceinline__ float bf2f(unsigned short s) {
    unsigned u = (unsigned)s << 16;
    float f;
    __builtin_memcpy(&f, &u, 4);
    return f;
}

// Barrier WITHOUT vmcnt drain.
static __device__ __forceinline__ void bar_nodrain() {
    __builtin_amdgcn_sched_barrier(0);
    asm volatile("s_waitcnt lgkmcnt(0)" ::: "memory");
    __builtin_amdgcn_s_barrier();
    __builtin_amdgcn_sched_barrier(0);
}

// ---------------------------------------------------------------------------
// hidden fp32 -> bf16
// ---------------------------------------------------------------------------
__global__ __launch_bounds__(256)
void cvt_bf16(const float* __restrict__ in, unsigned* __restrict__ out, int n8)
{
    const int i = blockIdx.x * 256 + threadIdx.x;
    if (i >= n8) return;
    f32x4 a = ((const f32x4*)in)[2 * i];
    f32x4 b = ((const f32x4*)in)[2 * i + 1];
    u32x4 p = { pack2(a[0], a[1]), pack2(a[2], a[3]), pack2(b[0], b[1]), pack2(b[2], b[3]) };
    ((u32x4*)out)[i] = p;
}

// ---------------------------------------------------------------------------
// BN=256 GEMM body (R11-measured best: 3.0 TB/s demand, VGPR 128, no spill).
// 512 threads = 8 waves (2M x 4N; per-wave 64x64). 1KB B-row slivers.
// A padded-72 LDS (free 2-way); Bs stride-33-dword. 1-deep A/B reg prefetch,
// no-drain barriers. bx = bidx % ntiles (tile-fast).
// ---------------------------------------------------------------------------
template<int CBF16, int COLMAP>
__device__ __forceinline__
void gemm_body256(const unsigned short* __restrict__ Ah, int lda,
                  const float* __restrict__ Bm, int ldb,
                  void* __restrict__ Cp, int ldc,
                  int kchunk, int ntiles, int bidx,
                  unsigned short* As, unsigned short* Bs)
{
    const int tid = threadIdx.x;
    const int l = tid & 63, lg = (l >> 4) & 3, l15 = l & 15;
    const int w = tid >> 6, wm = w >> 2, wn = w & 3;
    const int bx = bidx % ntiles;
    const int by = bidx / ntiles;
    const size_t k0base = (size_t)by * (size_t)kchunk;

    const int ar  = tid >> 2;            // A row 0..127
    const int ac  = (tid & 3) * 16;      // A ushort offset
    const int bnbt = (tid & 15) * 4 + ((tid >> 6) & 3) * 64;   // col 0..255
    const int bkk  = ((tid >> 4) & 3) + ((tid >> 8) << 2);     // k-pair 0..7
    const int gcol = (COLMAP ? (bx * 384) : (bx * 256)) + bnbt
                   + (COLMAP ? ((bnbt >> 7) << 6) : 0);

    u32x4 aReg[2];
    f32x4 bReg[4][2];

    auto loadA = [&](size_t k0) {
#pragma unroll
        for (int k = 0; k < 2; k++)
            aReg[k] = *(const u32x4*)(Ah + (size_t)ar * lda + k0 + ac + 8 * k);
    };
    auto storeA = [&]() {
#pragma unroll
        for (int k = 0; k < 2; k++)
            *(u32x4*)&As[ar * 72 + ac + 8 * k] = aReg[k];
    };
    auto loadB = [&](size_t k0) {
#pragma unroll
        for (int i = 0; i < 4; i++) {
            const float* bp = Bm + (k0 + (size_t)(2 * (bkk + 8 * i))) * (size_t)ldb + gcol;
            bReg[i][0] = *(const f32x4*)bp;
            bReg[i][1] = *(const f32x4*)(bp + ldb);
        }
    };
    auto storeB = [&]() {
        unsigned* bd = (unsigned*)Bs;
#pragma unroll
        for (int i = 0; i < 4; i++)
#pragma unroll
            for (int j = 0; j < 4; j++)
                bd[(bnbt + j) * 33 + bkk + 8 * i] = pack2(bReg[i][0][j], bReg[i][1][j]);
    };

    f32x4 acc[4][4];
    const f32x4 fzero = {0.f, 0.f, 0.f, 0.f};
#pragma unroll
    for (int a = 0; a < 4; a++)
#pragma unroll
        for (int b2 = 0; b2 < 4; b2++) acc[a][b2] = fzero;

    auto mfmaStep = [&]() {
#pragma unroll
        for (int ks = 0; ks < 2; ks++) {
            bf16x8 bfr[4];
#pragma unroll
            for (int nf = 0; nf < 4; nf++)
                bfr[nf] = *(const bf16x8*)&Bs[(64 * wn + 16 * nf + l15) * 66 + 32 * ks + 8 * lg];
#pragma unroll
            for (int mf = 0; mf < 4; mf++) {
                bf16x8 af = *(const bf16x8*)&As[(64 * wm + 16 * mf + l15) * 72 + 32 * ks + 8 * lg];
#pragma unroll
                for (int nf = 0; nf < 4; nf++)
                    acc[mf][nf] = __builtin_amdgcn_mfma_f32_16x16x32_bf16(af, bfr[nf], acc[mf][nf], 0, 0, 0);
            }
        }
    };

    const int nst = kchunk >> 6;
    loadA(k0base);
    loadB(k0base);

    for (int t = 0; t < nst; ++t) {
        storeA(); storeB();
        bar_nodrain();
        if (t + 1 < nst) {
            const size_t k0 = k0base + (size_t)((t + 1) << 6);
            loadA(k0); loadB(k0);
        }
        __builtin_amdgcn_sched_barrier(0);
        mfmaStep();
        bar_nodrain();
    }
#pragma unroll
    for (int mf = 0; mf < 4; mf++) {
#pragma unroll
        for (int nf = 0; nf < 4; nf++) {
            const int m0 = 64 * wm + 16 * mf + 4 * lg;
            const int cn = bx * 256 + 64 * wn + 16 * nf + l15;
            if (CBF16) {
                unsigned short* Ch = (unsigned short*)Cp + (size_t)by * ((size_t)128 * (size_t)ldc);
#pragma unroll
                for (int r = 0; r < 4; r++)
                    Ch[(size_t)(m0 + r) * ldc + cn] = f2bf(acc[mf][nf][r]);
            } else {
                float* Cf = (float*)Cp + (size_t)by * ((size_t)128 * (size_t)ldc);
#pragma unroll
                for (int r = 0; r < 4; r++)
                    Cf[(size_t)(m0 + r) * ldc + cn] = acc[mf][nf][r];
            }
        }
    }
}

// ---------------------------------------------------------------------------
// Fused projection: blocks [0,512) -> q partials (bf16, 64 tiles x 8 splits),
// [512,528) -> kv partials (fp32, 1 tile x 16 splits).
// ---------------------------------------------------------------------------
#define QBLOCKS 512

__global__ __launch_bounds__(512, 2)
void proj_fused(const unsigned short* __restrict__ hb,
                const float* __restrict__ Wq, const float* __restrict__ Wkv,
                unsigned short* __restrict__ qp, float* __restrict__ kvp)
{
    __shared__ __align__(16) unsigned short As[128 * 72];
    __shared__ __align__(16) unsigned short Bs[256 * 66];
    if (blockIdx.x < QBLOCKS)
        gemm_body256<1, 1>(hb, 5120, Wq, 24576, qp, 16384, 640, 64, blockIdx.x, As, Bs);
    else
        gemm_body256<0, 0>(hb, 5120, Wkv, 576, kvp, 256, 320, 1, blockIdx.x - QBLOCKS, As, Bs);
}

// ---------------------------------------------------------------------------
// out partials = attn(bf16) @ Wo, bf16 partials (20 tiles x 32 splits)
// ---------------------------------------------------------------------------
__global__ __launch_bounds__(512, 2)
void gemm_out(const unsigned short* __restrict__ Ah, const float* __restrict__ Wo,
              unsigned short* __restrict__ outp)
{
    __shared__ __align__(16) unsigned short As[128 * 72];
    __shared__ __align__(16) unsigned short Bs[256 * 66];
    gemm_body256<1, 0>(Ah, 16384, Wo, 5120, outp, 5120, 512, 20, blockIdx.x, As, Bs);
}

// ---------------------------------------------------------------------------
// reduce 8 bf16 q partials, fold softmax scale, pack to bf16.
// ---------------------------------------------------------------------------
__global__ __launch_bounds__(256)
void reduce_q_bf16(const unsigned short* __restrict__ in, unsigned* __restrict__ out)
{
    const int i = blockIdx.x * 256 + threadIdx.x;   // u32x4 units
    const u32x4* in4 = (const u32x4*)in;
    float lo[4] = {0.f, 0.f, 0.f, 0.f}, hi[4] = {0.f, 0.f, 0.f, 0.f};
#pragma unroll
    for (int j = 0; j < 8; j++) {
        u32x4 v = in4[i + (size_t)j * 262144];
#pragma unroll
        for (int wd = 0; wd < 4; wd++) {
            lo[wd] += bf2f((unsigned short)(v[wd] & 0xffff));
            hi[wd] += bf2f((unsigned short)(v[wd] >> 16));
        }
    }
    const float scale = 0.088388347648318447f;      // 1/sqrt(128)
    u32x4 r;
#pragma unroll
    for (int wd = 0; wd < 4; wd++) r[wd] = pack2(lo[wd] * scale, hi[wd] * scale);
    ((u32x4*)out)[i] = r;
}

// ---------------------------------------------------------------------------
// Flash-decode attention. KVBLK=64, grid (B, NSPLIT=8), block 512.
// ---------------------------------------------------------------------------
#define NSPLIT 8
#define CHUNK_T 8
#define KVSPLIT 16

__global__ __launch_bounds__(512, 4)
void attn_fwd(const float* __restrict__ kc, const float* __restrict__ vc,
              const unsigned short* __restrict__ qb, const float* __restrict__ kvp,
              const int* __restrict__ seq_lens, const int* __restrict__ slot_map,
              unsigned short* __restrict__ Opart, float* __restrict__ m_ws, float* __restrict__ l_ws)
{
    __shared__ __align__(16) unsigned short Ks [64 * 136];
    __shared__ __align__(16) unsigned short Vts[128 * 72];
    __shared__ __align__(16) unsigned short Ps [128 * 72];
    __shared__ float knew_s[128];
    __shared__ float vnew_s[128];

    const int b = blockIdx.x, split = blockIdx.y;
    const int seq = seq_lens[b], slot = slot_map[b];
    const int nt = (seq + 63) >> 6;
    const int t0 = split * CHUNK_T;
    const int t1 = min(t0 + CHUNK_T, nt);
    const int slotTile = slot >> 6;

    const int tid = threadIdx.x, w = tid >> 6, l = tid & 63, lg = l >> 4, l15 = l & 15;
    const int h = 16 * w + l15;

    float m_run = -__builtin_inff(), l_run = 0.0f;

    if (t0 < t1) {
        if (slotTile >= t0 && slotTile < t1 && tid < 256) {
            float s = 0.f;
#pragma unroll
            for (int j = 0; j < KVSPLIT; j++) s += kvp[j * 32768 + b * 256 + tid];
            if (tid < 128) knew_s[tid] = s;
            else           vnew_s[tid - 128] = s;
        }

        bf16x8 qf[4];
        {
            const unsigned short* qrow = qb + (size_t)b * 16384 + (size_t)h * 128;
#pragma unroll
            for (int ks = 0; ks < 4; ks++)
                qf[ks] = *(const bf16x8*)(qrow + 32 * ks + 8 * lg);
        }

        f32x4 kReg[4];
        f32x4 vReg[2][2];
        const int kr  = tid >> 3;
        const int kcb = (tid & 7) * 16;
        const int vsp = tid & 31;
        const int vdq = tid >> 5;

        auto loadKV = [&](int t) {
            const int s0 = t << 6;
            const float* ksrc = kc + ((size_t)b * 4096 + s0 + kr) * 128 + kcb;
#pragma unroll
            for (int c = 0; c < 4; c++) kReg[c] = *(const f32x4*)(ksrc + 4 * c);
#pragma unroll
            for (int i = 0; i < 2; i++) {
                const int d4 = 4 * vdq + 64 * i;
                const float* r1 = vc + ((size_t)b * 4096 + s0 + 2 * vsp) * 128 + d4;
                vReg[i][0] = *(const f32x4*)r1;
                vReg[i][1] = *(const f32x4*)(r1 + 128);
            }
        };
        auto storeKV = [&]() {
            u32x4 w0 = { pack2(kReg[0][0], kReg[0][1]), pack2(kReg[0][2], kReg[0][3]),
                         pack2(kReg[1][0], kReg[1][1]), pack2(kReg[1][2], kReg[1][3]) };
            u32x4 w1 = { pack2(kReg[2][0], kReg[2][1]), pack2(kReg[2][2], kReg[2][3]),
                         pack2(kReg[3][0], kReg[3][1]), pack2(kReg[3][2], kReg[3][3]) };
            *(u32x4*)&Ks[kr * 136 + kcb] = w0;
            *(u32x4*)&Ks[kr * 136 + kcb + 8] = w1;
            unsigned* vt = (unsigned*)Vts;
#pragma unroll
            for (int i = 0; i < 2; i++)
#pragma unroll
                for (int j = 0; j < 4; j++)
                    vt[(4 * vdq + 64 * i + j) * 36 + vsp] = pack2(vReg[i][0][j], vReg[i][1][j]);
        };

        f32x4 accO[8];
        const f32x4 fzero = {0.f, 0.f, 0.f, 0.f};
#pragma unroll
        for (int i = 0; i < 8; i++) accO[i] = fzero;

        loadKV(t0);
        for (int t = t0; t < t1; ++t) {
            const int s0 = t << 6;
            storeKV();
            bar_nodrain();
            if (t == slotTile) {
                if (tid < 128) {
                    const int sloc = slot & 63;
                    Ks [sloc * 136 + tid] = f2bf(knew_s[tid]);
                    Vts[tid * 72 + sloc]  = f2bf(vnew_s[tid]);
                }
                bar_nodrain();
            }
            if (t + 1 < t1) loadKV(t + 1);
            __builtin_amdgcn_sched_barrier(0);

            f32x4 accS[4];
#pragma unroll
            for (int sf = 0; sf < 4; sf++) accS[sf] = fzero;
#pragma unroll
            for (int ks = 0; ks < 4; ks++) {
#pragma unroll
                for (int sf = 0; sf < 4; sf++) {
                    bf16x8 kf = *(const bf16x8*)&Ks[(16 * sf + l15) * 136 + 32 * ks + 8 * lg];
                    accS[sf] = __builtin_amdgcn_mfma_f32_16x16x32_bf16(kf, qf[ks], accS[sf], 0, 0, 0);
                }
            }
            float tmax = -__builtin_inff();
#pragma unroll
            for (int sf = 0; sf < 4; sf++) {
#pragma unroll
                for (int r = 0; r < 4; r++) {
                    const int s = s0 + 16 * sf + 4 * lg + r;
                    float sc = (s < seq) ? accS[sf][r] : -__builtin_inff();
                    accS[sf][r] = sc;
                    tmax = fmaxf(tmax, sc);
                }
            }
            tmax = fmaxf(tmax, __shfl_xor(tmax, 16));
            tmax = fmaxf(tmax, __shfl_xor(tmax, 32));
            const float mnew = fmaxf(m_run, tmax);
            const float so = __expf(m_run - mnew);
            float lsum = 0.f;
#pragma unroll
            for (int sf = 0; sf < 4; sf++) {
#pragma unroll
                for (int r = 0; r < 4; r++) {
                    const float p = __expf(accS[sf][r] - mnew);
                    accS[sf][r] = p;
                    lsum += p;
                }
            }
            lsum += __shfl_xor(lsum, 16);
            lsum += __shfl_xor(lsum, 32);
            l_run = l_run * so + lsum;
            m_run = mnew;
#pragma unroll
            for (int i = 0; i < 8; i++) accO[i] *= so;

            {
                unsigned* pd = (unsigned*)Ps;
#pragma unroll
                for (int sf = 0; sf < 4; sf++) {
                    pd[h * 36 + 8 * sf + 2 * lg + 0] = pack2(accS[sf][0], accS[sf][1]);
                    pd[h * 36 + 8 * sf + 2 * lg + 1] = pack2(accS[sf][2], accS[sf][3]);
                }
            }
            bf16x8 pf[2];
#pragma unroll
            for (int ks = 0; ks < 2; ks++)
                pf[ks] = *(const bf16x8*)&Ps[h * 72 + 32 * ks + 8 * lg];
#pragma unroll
            for (int df = 0; df < 8; df++) {
#pragma unroll
                for (int ks = 0; ks < 2; ks++) {
                    bf16x8 vf = *(const bf16x8*)&Vts[(16 * df + l15) * 72 + 32 * ks + 8 * lg];
                    accO[df] = __builtin_amdgcn_mfma_f32_16x16x32_bf16(vf, pf[ks], accO[df], 0, 0, 0);
                }
            }
            bar_nodrain();
        }
        unsigned short* ob = Opart + ((size_t)(b * NSPLIT + split)) * 16384 + (size_t)h * 128;
#pragma unroll
        for (int df = 0; df < 8; df++) {
            u32x2 p = { pack2(accO[df][0], accO[df][1]), pack2(accO[df][2], accO[df][3]) };
            *(u32x2*)&ob[16 * df + 4 * lg] = p;
        }
    }
    if (lg == 0) {
        m_ws[(b * NSPLIT + split) * 128 + h] = m_run;
        l_ws[(b * NSPLIT + split) * 128 + h] = l_run;
    }
}

// ---------------------------------------------------------------------------
// Combine the 8 S-split bf16 partials -> bf16 attn.
// ---------------------------------------------------------------------------
__global__ __launch_bounds__(256)
void combine8(const unsigned short* __restrict__ Opart, const float* __restrict__ m_ws,
              const float* __restrict__ l_ws, unsigned* __restrict__ attn_bf)
{
    const int idx = blockIdx.x * 256 + threadIdx.x;
    const int d4 = (idx & 31) * 4;
    const int hh = (idx >> 5) & 127;
    const int b = idx >> 12;

    float m = -__builtin_inff();
    float mv[NSPLIT], lv[NSPLIT];
#pragma unroll
    for (int j = 0; j < NSPLIT; j++) {
        mv[j] = m_ws[(b * NSPLIT + j) * 128 + hh];
        lv[j] = l_ws[(b * NSPLIT + j) * 128 + hh];
        m = fmaxf(m, mv[j]);
    }
    f32x4 o = {0.f, 0.f, 0.f, 0.f};
    float lsum = 0.f;
#pragma unroll
    for (int j = 0; j < NSPLIT; j++) {
        const float a = (lv[j] > 0.f) ? __expf(mv[j] - m) : 0.f;
        lsum += a * lv[j];
        if (a > 0.f) {
            u32x2 v = *(const u32x2*)&Opart[((size_t)(b * NSPLIT + j)) * 16384 + (size_t)hh * 128 + d4];
            f32x4 oj = { bf2f((unsigned short)(v[0] & 0xffff)), bf2f((unsigned short)(v[0] >> 16)),
                         bf2f((unsigned short)(v[1] & 0xffff)), bf2f((unsigned short)(v[1] >> 16)) };
            o += oj * a;
        }
    }
    o *= (1.0f / lsum);
    u32x2 p = { pack2(o[0], o[1]), pack2(o[2], o[3]) };
    *(u32x2*)&attn_bf[(size_t)b * 8192 + (size_t)hh * 64 + (d4 >> 1)] = p;
}

// ---------------------------------------------------------------------------
// reduce 32 bf16 out partials -> fp32 out
// ---------------------------------------------------------------------------
__global__ __launch_bounds__(256)
void reduce_out_f32(const unsigned short* __restrict__ in, float* __restrict__ out)
{
    const int i = blockIdx.x * 256 + threadIdx.x;   // 0..163839, 4 floats each
    f32x4 s = {0.f, 0.f, 0.f, 0.f};
#pragma unroll
    for (int j = 0; j < 32; j++) {
        u32x2 v = *(const u32x2*)&in[(size_t)j * 655360 + 4 * (size_t)i];
        s[0] += bf2f((unsigned short)(v[0] & 0xffff));
        s[1] += bf2f((unsigned short)(v[0] >> 16));
        s[2] += bf2f((unsigned short)(v[1] & 0xffff));
        s[3] += bf2f((unsigned short)(v[1] >> 16));
    }
    ((f32x4*)out)[i] = s;
}

// ---------------------------------------------------------------------------
extern "C" void kernel_launch(void* const* d_in, const int* in_sizes, int n_in,
                              void* d_out, int out_size, void* d_ws, size_t ws_size,
                              hipStream_t stream)
{
    const float* hidden  = (const float*)d_in[0];
    const float* k_cache = (const float*)d_in[1];
    const float* v_cache = (const float*)d_in[2];
    const float* Wq      = (const float*)d_in[3];
    const float* Wkv     = (const float*)d_in[4];
    const float* Wo      = (const float*)d_in[5];
    const int* slot_map  = (const int*)d_in[7];
    const int* seq_lens  = (const int*)d_in[8];
    float* out = (float*)d_out;

    float* ws = (float*)d_ws;                                    // float units
    unsigned short* hb      = (unsigned short*)(ws);             //    327,680 f
    unsigned short* qp      = (unsigned short*)(ws + 327680);    //  8,388,608 f (8 splits bf16)
    unsigned short* qb      = (unsigned short*)(ws + 8716288);   //  1,048,576 f
    float*          kvp     = ws + 9764864;                      //    524,288 f (16 splits f32)
    unsigned short* attn_bf = (unsigned short*)(ws + 10289152);  //  1,048,576 f
    unsigned short* Opart   = (unsigned short*)(ws + 11337728);  //  8,388,608 f
    float*          m_ws    = ws + 19726336;                     //    131,072 f
    float*          l_ws    = ws + 19857408;                     //    131,072 f
    unsigned short* outp    = (unsigned short*)(ws + 19988480);  // 10,485,760 f (32 splits bf16)

    // hidden -> bf16
    cvt_bf16<<<dim3(320), 256, 0, stream>>>(hidden, (unsigned*)hb, 81920);
    // fused: q partials (bf16, 64 tiles x 8 splits) + kv partials (fp32, 16 splits)
    proj_fused<<<dim3(QBLOCKS + 16), 512, 0, stream>>>(hb, Wq, Wkv, qp, kvp);
    // q reduce -> scaled bf16
    reduce_q_bf16<<<dim3(1024), 256, 0, stream>>>(qp, (unsigned*)qb);
    // attention (8 chunked S-splits per batch; kv-reduce fused; bf16 Opart)
    attn_fwd<<<dim3(128, NSPLIT), 512, 0, stream>>>(k_cache, v_cache, qb, kvp,
                                                    seq_lens, slot_map, Opart, m_ws, l_ws);
    combine8<<<dim3(2048), 256, 0, stream>>>(Opart, m_ws, l_ws, (unsigned*)attn_bf);
    // out partials = attn(bf16) @ Wo (20 tiles x 32 splits)
    gemm_out<<<dim3(20 * 32), 512, 0, stream>>>(attn_bf, Wo, outp);
    reduce_out_f32<<<dim3(640), 256, 0, stream>>>(outp, out);
}

// Round 14
// 309.316 us; speedup vs baseline: 7.2541x; 1.0076x over previous
//
#include <hip/hip_runtime.h>
#include <hip/hip_bf16.h>

typedef __attribute__((ext_vector_type(4))) float f32x4;
typedef __attribute__((ext_vector_type(8))) short bf16x8;
typedef __attribute__((ext_vector_type(2))) unsigned int u32x2;
typedef __attribute__((ext_vector_type(4))) unsigned int u32x4;

static __device__ __forceinline__ unsigned short f2bf(float f) {
    unsigned u = __builtin_bit_cast(unsigned, f);
    u += 0x7fffu + ((u >> 16) & 1u);   // RNE
    return (unsigned short)(u >> 16);
}
static __device__ __forceinline__ unsigned pack2(float a, float b) {
    __hip_bfloat162 h = __float22bfloat162_rn(make_float2(a, b));  // v_cvt_pk_bf16_f32
    unsigned u;
    __builtin_memcpy(&u, &h, 4);
    return u;
}
static __device__ __forceinline__ float bf2f(unsigned short s) {
    unsigned u = (unsigned)s << 16;
    float f;
    __builtin_memcpy(&f, &u, 4);
    return f;
}

// Barrier WITHOUT vmcnt drain.
static __device__ __forceinline__ void bar_nodrain() {
    __builtin_amdgcn_sched_barrier(0);
    asm volatile("s_waitcnt lgkmcnt(0)" ::: "memory");
    __builtin_amdgcn_s_barrier();
    __builtin_amdgcn_sched_barrier(0);
}

// ---------------------------------------------------------------------------
// hidden fp32 -> bf16
// ---------------------------------------------------------------------------
__global__ __launch_bounds__(256)
void cvt_bf16(const float* __restrict__ in, unsigned* __restrict__ out, int n8)
{
    const int i = blockIdx.x * 256 + threadIdx.x;
    if (i >= n8) return;
    f32x4 a = ((const f32x4*)in)[2 * i];
    f32x4 b = ((const f32x4*)in)[2 * i + 1];
    u32x4 p = { pack2(a[0], a[1]), pack2(a[2], a[3]), pack2(b[0], b[1]), pack2(b[2], b[3]) };
    ((u32x4*)out)[i] = p;
}

// ---------------------------------------------------------------------------
// BN=256 GEMM body (R11/R13-measured best). 512 threads = 8 waves (2M x 4N).
// ---------------------------------------------------------------------------
template<int CBF16, int COLMAP>
__device__ __forceinline__
void gemm_body256(const unsigned short* __restrict__ Ah, int lda,
                  const float* __restrict__ Bm, int ldb,
                  void* __restrict__ Cp, int ldc,
                  int kchunk, int ntiles, int bidx,
                  unsigned short* As, unsigned short* Bs)
{
    const int tid = threadIdx.x;
    const int l = tid & 63, lg = (l >> 4) & 3, l15 = l & 15;
    const int w = tid >> 6, wm = w >> 2, wn = w & 3;
    const int bx = bidx % ntiles;
    const int by = bidx / ntiles;
    const size_t k0base = (size_t)by * (size_t)kchunk;

    const int ar  = tid >> 2;            // A row 0..127
    const int ac  = (tid & 3) * 16;      // A ushort offset
    const int bnbt = (tid & 15) * 4 + ((tid >> 6) & 3) * 64;   // col 0..255
    const int bkk  = ((tid >> 4) & 3) + ((tid >> 8) << 2);     // k-pair 0..7
    const int gcol = (COLMAP ? (bx * 384) : (bx * 256)) + bnbt
                   + (COLMAP ? ((bnbt >> 7) << 6) : 0);

    u32x4 aReg[2];
    f32x4 bReg[4][2];

    auto loadA = [&](size_t k0) {
#pragma unroll
        for (int k = 0; k < 2; k++)
            aReg[k] = *(const u32x4*)(Ah + (size_t)ar * lda + k0 + ac + 8 * k);
    };
    auto storeA = [&]() {
#pragma unroll
        for (int k = 0; k < 2; k++)
            *(u32x4*)&As[ar * 72 + ac + 8 * k] = aReg[k];
    };
    auto loadB = [&](size_t k0) {
#pragma unroll
        for (int i = 0; i < 4; i++) {
            const float* bp = Bm + (k0 + (size_t)(2 * (bkk + 8 * i))) * (size_t)ldb + gcol;
            bReg[i][0] = *(const f32x4*)bp;
            bReg[i][1] = *(const f32x4*)(bp + ldb);
        }
    };
    auto storeB = [&]() {
        unsigned* bd = (unsigned*)Bs;
#pragma unroll
        for (int i = 0; i < 4; i++)
#pragma unroll
            for (int j = 0; j < 4; j++)
                bd[(bnbt + j) * 33 + bkk + 8 * i] = pack2(bReg[i][0][j], bReg[i][1][j]);
    };

    f32x4 acc[4][4];
    const f32x4 fzero = {0.f, 0.f, 0.f, 0.f};
#pragma unroll
    for (int a = 0; a < 4; a++)
#pragma unroll
        for (int b2 = 0; b2 < 4; b2++) acc[a][b2] = fzero;

    auto mfmaStep = [&]() {
#pragma unroll
        for (int ks = 0; ks < 2; ks++) {
            bf16x8 bfr[4];
#pragma unroll
            for (int nf = 0; nf < 4; nf++)
                bfr[nf] = *(const bf16x8*)&Bs[(64 * wn + 16 * nf + l15) * 66 + 32 * ks + 8 * lg];
#pragma unroll
            for (int mf = 0; mf < 4; mf++) {
                bf16x8 af = *(const bf16x8*)&As[(64 * wm + 16 * mf + l15) * 72 + 32 * ks + 8 * lg];
#pragma unroll
                for (int nf = 0; nf < 4; nf++)
                    acc[mf][nf] = __builtin_amdgcn_mfma_f32_16x16x32_bf16(af, bfr[nf], acc[mf][nf], 0, 0, 0);
            }
        }
    };

    const int nst = kchunk >> 6;
    loadA(k0base);
    loadB(k0base);

    for (int t = 0; t < nst; ++t) {
        storeA(); storeB();
        bar_nodrain();
        if (t + 1 < nst) {
            const size_t k0 = k0base + (size_t)((t + 1) << 6);
            loadA(k0); loadB(k0);
        }
        __builtin_amdgcn_sched_barrier(0);
        mfmaStep();
        bar_nodrain();
    }
#pragma unroll
    for (int mf = 0; mf < 4; mf++) {
#pragma unroll
        for (int nf = 0; nf < 4; nf++) {
            const int m0 = 64 * wm + 16 * mf + 4 * lg;
            const int cn = bx * 256 + 64 * wn + 16 * nf + l15;
            if (CBF16) {
                unsigned short* Ch = (unsigned short*)Cp + (size_t)by * ((size_t)128 * (size_t)ldc);
#pragma unroll
                for (int r = 0; r < 4; r++)
                    Ch[(size_t)(m0 + r) * ldc + cn] = f2bf(acc[mf][nf][r]);
            } else {
                float* Cf = (float*)Cp + (size_t)by * ((size_t)128 * (size_t)ldc);
#pragma unroll
                for (int r = 0; r < 4; r++)
                    Cf[(size_t)(m0 + r) * ldc + cn] = acc[mf][nf][r];
            }
        }
    }
}

// ---------------------------------------------------------------------------
// Fused projection: blocks [0,512) -> q partials (bf16, 64 tiles x 8 splits),
// [512,528) -> kv partials (fp32, 1 tile x 16 splits).
// ---------------------------------------------------------------------------
#define QBLOCKS 512

__global__ __launch_bounds__(512, 2)
void proj_fused(const unsigned short* __restrict__ hb,
                const float* __restrict__ Wq, const float* __restrict__ Wkv,
                unsigned short* __restrict__ qp, float* __restrict__ kvp)
{
    __shared__ __align__(16) unsigned short As[128 * 72];
    __shared__ __align__(16) unsigned short Bs[256 * 66];
    if (blockIdx.x < QBLOCKS)
        gemm_body256<1, 1>(hb, 5120, Wq, 24576, qp, 16384, 640, 64, blockIdx.x, As, Bs);
    else
        gemm_body256<0, 0>(hb, 5120, Wkv, 576, kvp, 256, 320, 1, blockIdx.x - QBLOCKS, As, Bs);
}

// ---------------------------------------------------------------------------
// out partials = attn(bf16) @ Wo, bf16 partials (20 tiles x 32 splits)
// ---------------------------------------------------------------------------
__global__ __launch_bounds__(512, 2)
void gemm_out(const unsigned short* __restrict__ Ah, const float* __restrict__ Wo,
              unsigned short* __restrict__ outp)
{
    __shared__ __align__(16) unsigned short As[128 * 72];
    __shared__ __align__(16) unsigned short Bs[256 * 66];
    gemm_body256<1, 0>(Ah, 16384, Wo, 5120, outp, 5120, 512, 20, blockIdx.x, As, Bs);
}

// ---------------------------------------------------------------------------
// reduce 8 bf16 q partials, fold softmax scale, pack to bf16.
// ---------------------------------------------------------------------------
__global__ __launch_bounds__(256)
void reduce_q_bf16(const unsigned short* __restrict__ in, unsigned* __restrict__ out)
{
    const int i = blockIdx.x * 256 + threadIdx.x;   // u32x4 units
    const u32x4* in4 = (const u32x4*)in;
    float lo[4] = {0.f, 0.f, 0.f, 0.f}, hi[4] = {0.f, 0.f, 0.f, 0.f};
#pragma unroll
    for (int j = 0; j < 8; j++) {
        u32x4 v = in4[i + (size_t)j * 262144];
#pragma unroll
        for (int wd = 0; wd < 4; wd++) {
            lo[wd] += bf2f((unsigned short)(v[wd] & 0xffff));
            hi[wd] += bf2f((unsigned short)(v[wd] >> 16));
        }
    }
    const float scale = 0.088388347648318447f;      // 1/sqrt(128)
    u32x4 r;
#pragma unroll
    for (int wd = 0; wd < 4; wd++) r[wd] = pack2(lo[wd] * scale, hi[wd] * scale);
    ((u32x4*)out)[i] = r;
}

// ---------------------------------------------------------------------------
// Flash-decode attention. KVBLK=64, grid (B, NSPLIT=8), block 512.
// STRIDED split assignment: split s owns tiles {s, s+8, s+16, ...} -> every
// block gets ceil(nt/8)±1 tiles regardless of seq (online softmax is
// order-invariant). kv-reduce fused; slot row patched post-staging.
// ---------------------------------------------------------------------------
#define NSPLIT 8
#define KVSPLIT 16

__global__ __launch_bounds__(512, 4)
void attn_fwd(const float* __restrict__ kc, const float* __restrict__ vc,
              const unsigned short* __restrict__ qb, const float* __restrict__ kvp,
              const int* __restrict__ seq_lens, const int* __restrict__ slot_map,
              unsigned short* __restrict__ Opart, float* __restrict__ m_ws, float* __restrict__ l_ws)
{
    __shared__ __align__(16) unsigned short Ks [64 * 136];
    __shared__ __align__(16) unsigned short Vts[128 * 72];
    __shared__ __align__(16) unsigned short Ps [128 * 72];
    __shared__ float knew_s[128];
    __shared__ float vnew_s[128];

    const int b = blockIdx.x, split = blockIdx.y;
    const int seq = seq_lens[b], slot = slot_map[b];
    const int nt = (seq + 63) >> 6;
    const int slotTile = slot >> 6;

    const int tid = threadIdx.x, w = tid >> 6, l = tid & 63, lg = l >> 4, l15 = l & 15;
    const int h = 16 * w + l15;

    float m_run = -__builtin_inff(), l_run = 0.0f;

    if (split < nt) {
        // this split owns slotTile iff slotTile ≡ split (mod NSPLIT)
        if ((slotTile & (NSPLIT - 1)) == split && tid < 256) {
            float s = 0.f;
#pragma unroll
            for (int j = 0; j < KVSPLIT; j++) s += kvp[j * 32768 + b * 256 + tid];
            if (tid < 128) knew_s[tid] = s;
            else           vnew_s[tid - 128] = s;
        }

        bf16x8 qf[4];
        {
            const unsigned short* qrow = qb + (size_t)b * 16384 + (size_t)h * 128;
#pragma unroll
            for (int ks = 0; ks < 4; ks++)
                qf[ks] = *(const bf16x8*)(qrow + 32 * ks + 8 * lg);
        }

        f32x4 kReg[4];
        f32x4 vReg[2][2];
        const int kr  = tid >> 3;
        const int kcb = (tid & 7) * 16;
        const int vsp = tid & 31;
        const int vdq = tid >> 5;

        auto loadKV = [&](int t) {
            const int s0 = t << 6;
            const float* ksrc = kc + ((size_t)b * 4096 + s0 + kr) * 128 + kcb;
#pragma unroll
            for (int c = 0; c < 4; c++) kReg[c] = *(const f32x4*)(ksrc + 4 * c);
#pragma unroll
            for (int i = 0; i < 2; i++) {
                const int d4 = 4 * vdq + 64 * i;
                const float* r1 = vc + ((size_t)b * 4096 + s0 + 2 * vsp) * 128 + d4;
                vReg[i][0] = *(const f32x4*)r1;
                vReg[i][1] = *(const f32x4*)(r1 + 128);
            }
        };
        auto storeKV = [&]() {
            u32x4 w0 = { pack2(kReg[0][0], kReg[0][1]), pack2(kReg[0][2], kReg[0][3]),
                         pack2(kReg[1][0], kReg[1][1]), pack2(kReg[1][2], kReg[1][3]) };
            u32x4 w1 = { pack2(kReg[2][0], kReg[2][1]), pack2(kReg[2][2], kReg[2][3]),
                         pack2(kReg[3][0], kReg[3][1]), pack2(kReg[3][2], kReg[3][3]) };
            *(u32x4*)&Ks[kr * 136 + kcb] = w0;
            *(u32x4*)&Ks[kr * 136 + kcb + 8] = w1;
            unsigned* vt = (unsigned*)Vts;
#pragma unroll
            for (int i = 0; i < 2; i++)
#pragma unroll
                for (int j = 0; j < 4; j++)
                    vt[(4 * vdq + 64 * i + j) * 36 + vsp] = pack2(vReg[i][0][j], vReg[i][1][j]);
        };

        f32x4 accO[8];
        const f32x4 fzero = {0.f, 0.f, 0.f, 0.f};
#pragma unroll
        for (int i = 0; i < 8; i++) accO[i] = fzero;

        loadKV(split);
        for (int t = split; t < nt; t += NSPLIT) {
            const int s0 = t << 6;
            storeKV();
            bar_nodrain();
            if (t == slotTile) {
                if (tid < 128) {
                    const int sloc = slot & 63;
                    Ks [sloc * 136 + tid] = f2bf(knew_s[tid]);
                    Vts[tid * 72 + sloc]  = f2bf(vnew_s[tid]);
                }
                bar_nodrain();
            }
            if (t + NSPLIT < nt) loadKV(t + NSPLIT);
            __builtin_amdgcn_sched_barrier(0);

            f32x4 accS[4];
#pragma unroll
            for (int sf = 0; sf < 4; sf++) accS[sf] = fzero;
#pragma unroll
            for (int ks = 0; ks < 4; ks++) {
#pragma unroll
                for (int sf = 0; sf < 4; sf++) {
                    bf16x8 kf = *(const bf16x8*)&Ks[(16 * sf + l15) * 136 + 32 * ks + 8 * lg];
                    accS[sf] = __builtin_amdgcn_mfma_f32_16x16x32_bf16(kf, qf[ks], accS[sf], 0, 0, 0);
                }
            }
            float tmax = -__builtin_inff();
#pragma unroll
            for (int sf = 0; sf < 4; sf++) {
#pragma unroll
                for (int r = 0; r < 4; r++) {
                    const int s = s0 + 16 * sf + 4 * lg + r;
                    float sc = (s < seq) ? accS[sf][r] : -__builtin_inff();
                    accS[sf][r] = sc;
                    tmax = fmaxf(tmax, sc);
                }
            }
            tmax = fmaxf(tmax, __shfl_xor(tmax, 16));
            tmax = fmaxf(tmax, __shfl_xor(tmax, 32));
            const float mnew = fmaxf(m_run, tmax);
            const float so = __expf(m_run - mnew);
            float lsum = 0.f;
#pragma unroll
            for (int sf = 0; sf < 4; sf++) {
#pragma unroll
                for (int r = 0; r < 4; r++) {
                    const float p = __expf(accS[sf][r] - mnew);
                    accS[sf][r] = p;
                    lsum += p;
                }
            }
            lsum += __shfl_xor(lsum, 16);
            lsum += __shfl_xor(lsum, 32);
            l_run = l_run * so + lsum;
            m_run = mnew;
#pragma unroll
            for (int i = 0; i < 8; i++) accO[i] *= so;

            {
                unsigned* pd = (unsigned*)Ps;
#pragma unroll
                for (int sf = 0; sf < 4; sf++) {
                    pd[h * 36 + 8 * sf + 2 * lg + 0] = pack2(accS[sf][0], accS[sf][1]);
                    pd[h * 36 + 8 * sf + 2 * lg + 1] = pack2(accS[sf][2], accS[sf][3]);
                }
            }
            bf16x8 pf[2];
#pragma unroll
            for (int ks = 0; ks < 2; ks++)
                pf[ks] = *(const bf16x8*)&Ps[h * 72 + 32 * ks + 8 * lg];
#pragma unroll
            for (int df = 0; df < 8; df++) {
#pragma unroll
                for (int ks = 0; ks < 2; ks++) {
                    bf16x8 vf = *(const bf16x8*)&Vts[(16 * df + l15) * 72 + 32 * ks + 8 * lg];
                    accO[df] = __builtin_amdgcn_mfma_f32_16x16x32_bf16(vf, pf[ks], accO[df], 0, 0, 0);
                }
            }
            bar_nodrain();
        }
        unsigned short* ob = Opart + ((size_t)(b * NSPLIT + split)) * 16384 + (size_t)h * 128;
#pragma unroll
        for (int df = 0; df < 8; df++) {
            u32x2 p = { pack2(accO[df][0], accO[df][1]), pack2(accO[df][2], accO[df][3]) };
            *(u32x2*)&ob[16 * df + 4 * lg] = p;
        }
    }
    if (lg == 0) {
        m_ws[(b * NSPLIT + split) * 128 + h] = m_run;
        l_ws[(b * NSPLIT + split) * 128 + h] = l_run;
    }
}

// ---------------------------------------------------------------------------
// Combine the 8 S-split bf16 partials -> bf16 attn.
// ---------------------------------------------------------------------------
__global__ __launch_bounds__(256)
void combine8(const unsigned short* __restrict__ Opart, const float* __restrict__ m_ws,
              const float* __restrict__ l_ws, unsigned* __restrict__ attn_bf)
{
    const int idx = blockIdx.x * 256 + threadIdx.x;
    const int d4 = (idx & 31) * 4;
    const int hh = (idx >> 5) & 127;
    const int b = idx >> 12;

    float m = -__builtin_inff();
    float mv[NSPLIT], lv[NSPLIT];
#pragma unroll
    for (int j = 0; j < NSPLIT; j++) {
        mv[j] = m_ws[(b * NSPLIT + j) * 128 + hh];
        lv[j] = l_ws[(b * NSPLIT + j) * 128 + hh];
        m = fmaxf(m, mv[j]);
    }
    f32x4 o = {0.f, 0.f, 0.f, 0.f};
    float lsum = 0.f;
#pragma unroll
    for (int j = 0; j < NSPLIT; j++) {
        const float a = (lv[j] > 0.f) ? __expf(mv[j] - m) : 0.f;
        lsum += a * lv[j];
        if (a > 0.f) {
            u32x2 v = *(const u32x2*)&Opart[((size_t)(b * NSPLIT + j)) * 16384 + (size_t)hh * 128 + d4];
            f32x4 oj = { bf2f((unsigned short)(v[0] & 0xffff)), bf2f((unsigned short)(v[0] >> 16)),
                         bf2f((unsigned short)(v[1] & 0xffff)), bf2f((unsigned short)(v[1] >> 16)) };
            o += oj * a;
        }
    }
    o *= (1.0f / lsum);
    u32x2 p = { pack2(o[0], o[1]), pack2(o[2], o[3]) };
    *(u32x2*)&attn_bf[(size_t)b * 8192 + (size_t)hh * 64 + (d4 >> 1)] = p;
}

// ---------------------------------------------------------------------------
// reduce 32 bf16 out partials -> fp32 out
// ---------------------------------------------------------------------------
__global__ __launch_bounds__(256)
void reduce_out_f32(const unsigned short* __restrict__ in, float* __restrict__ out)
{
    const int i = blockIdx.x * 256 + threadIdx.x;   // 0..163839, 4 floats each
    f32x4 s = {0.f, 0.f, 0.f, 0.f};
#pragma unroll
    for (int j = 0; j < 32; j++) {
        u32x2 v = *(const u32x2*)&in[(size_t)j * 655360 + 4 * (size_t)i];
        s[0] += bf2f((unsigned short)(v[0] & 0xffff));
        s[1] += bf2f((unsigned short)(v[0] >> 16));
        s[2] += bf2f((unsigned short)(v[1] & 0xffff));
        s[3] += bf2f((unsigned short)(v[1] >> 16));
    }
    ((f32x4*)out)[i] = s;
}

// ---------------------------------------------------------------------------
extern "C" void kernel_launch(void* const* d_in, const int* in_sizes, int n_in,
                              void* d_out, int out_size, void* d_ws, size_t ws_size,
                              hipStream_t stream)
{
    const float* hidden  = (const float*)d_in[0];
    const float* k_cache = (const float*)d_in[1];
    const float* v_cache = (const float*)d_in[2];
    const float* Wq      = (const float*)d_in[3];
    const float* Wkv     = (const float*)d_in[4];
    const float* Wo      = (const float*)d_in[5];
    const int* slot_map  = (const int*)d_in[7];
    const int* seq_lens  = (const int*)d_in[8];
    float* out = (float*)d_out;

    float* ws = (float*)d_ws;                                    // float units
    unsigned short* hb      = (unsigned short*)(ws);             //    327,680 f
    unsigned short* qp      = (unsigned short*)(ws + 327680);    //  8,388,608 f (8 splits bf16)
    unsigned short* qb      = (unsigned short*)(ws + 8716288);   //  1,048,576 f
    float*          kvp     = ws + 9764864;                      //    524,288 f (16 splits f32)
    unsigned short* attn_bf = (unsigned short*)(ws + 10289152);  //  1,048,576 f
    unsigned short* Opart   = (unsigned short*)(ws + 11337728);  //  8,388,608 f
    float*          m_ws    = ws + 19726336;                     //    131,072 f
    float*          l_ws    = ws + 19857408;                     //    131,072 f
    unsigned short* outp    = (unsigned short*)(ws + 19988480);  // 10,485,760 f (32 splits bf16)

    // hidden -> bf16
    cvt_bf16<<<dim3(320), 256, 0, stream>>>(hidden, (unsigned*)hb, 81920);
    // fused: q partials (bf16, 64 tiles x 8 splits) + kv partials (fp32, 16 splits)
    proj_fused<<<dim3(QBLOCKS + 16), 512, 0, stream>>>(hb, Wq, Wkv, qp, kvp);
    // q reduce -> scaled bf16
    reduce_q_bf16<<<dim3(1024), 256, 0, stream>>>(qp, (unsigned*)qb);
    // attention (8 STRIDED S-splits per batch; kv-reduce fused; bf16 Opart)
    attn_fwd<<<dim3(128, NSPLIT), 512, 0, stream>>>(k_cache, v_cache, qb, kvp,
                                                    seq_lens, slot_map, Opart, m_ws, l_ws);
    combine8<<<dim3(2048), 256, 0, stream>>>(Opart, m_ws, l_ws, (unsigned*)attn_bf);
    // out partials = attn(bf16) @ Wo (20 tiles x 32 splits)
    gemm_out<<<dim3(20 * 32), 512, 0, stream>>>(attn_bf, Wo, outp);
    reduce_out_f32<<<dim3(640), 256, 0, stream>>>(outp, out);
}